// Round 2
// baseline (2278.949 us; speedup 1.0000x reference)
//
#include <hip/hip_runtime.h>
#include <math.h>

#define NB   4       // batch elements per block (and per thread)
#define BLK  128     // threads per block = H
#define HDIM 128
#define TSTEPS 40
#define BTOT 16384

__global__ __launch_bounds__(BLK, 2)
void lsnn_kernel(const float* __restrict__ x,
                 const float* __restrict__ w_in,
                 const float* __restrict__ w_rec,
                 const float* __restrict__ w_out,
                 const float* __restrict__ dm,
                 float* __restrict__ out)
{
    __shared__ float xt[NB][8];              // encoder spikes for this step
    __shared__ unsigned int lmask[NB][4];    // z bitmasks (prev step): word q = bits h=q*32..q*32+31
    __shared__ float red[NB][2][2];          // [nb][wave][o] readout partial sums
    __shared__ float rout[NB][6];            // vo0,vo1,io0,io1,mx0,mx1

    const int tid  = threadIdx.x;
    const int hh   = tid;                    // hidden neuron index 0..127
    const int lane = tid & 63;
    const int wv   = tid >> 6;               // wave 0/1
    const long bbase = (long)blockIdx.x * NB;

    // --- my w_rec row in registers (one-time, L2-served; w_rec is 64KB hot) ---
    float w[HDIM];
    #pragma unroll
    for (int j = 0; j < HDIM; ++j) w[j] = w_rec[hh * HDIM + j];

    float win[8];
    #pragma unroll
    for (int s = 0; s < 8; ++s) win[s] = w_in[hh * 8 + s];
    const float wout0 = w_out[hh];
    const float wout1 = w_out[HDIM + hh];

    // --- encoder state (lanes 0..7 meaningful: channel hh, pos for hh<4, neg for 4..7) ---
    float ve[NB], ce[NB];
    #pragma unroll
    for (int nb = 0; nb < NB; ++nb) { ve[nb] = 0.f; ce[nb] = 0.f; }
    if (hh < 8) {
        #pragma unroll
        for (int nb = 0; nb < NB; ++nb) {
            float xv = 50.f * x[(bbase + nb) * 4 + (hh & 3)];
            ce[nb] = (hh < 4) ? fmaxf(xv, 0.f) : fmaxf(-xv, 0.f);
        }
    }

    if (tid < NB * 4) ((unsigned int*)lmask)[tid] = 0u;
    if (tid < NB * 6) ((float*)rout)[tid] = 0.f;   // vo(t=0)=0 so mx init 0 is exact

    float v[NB], cur[NB], ba[NB];
    #pragma unroll
    for (int nb = 0; nb < NB; ++nb) { v[nb] = 0.f; cur[nb] = 0.f; ba[nb] = 0.f; }

    const float KA = 1.4285714285714286e-06f;  // DT * (1/700)
    const float KB = 2.5714285714285714e-03f;  // (1/700) * 1.8

    for (int t = 0; t < TSTEPS; ++t) {
        // ---- encoder step (produces x_t used THIS step) ----
        if (hh < 8) {
            #pragma unroll
            for (int nb = 0; nb < NB; ++nb) {
                float vv = ve[nb] + 0.1f * (ce[nb] - ve[nb]);
                float sp = (vv - 1.0f > 0.f) ? 1.f : 0.f;
                ve[nb] = (1.f - sp) * vv;
                xt[nb][hh] = sp;
            }
        }
        __syncthreads();   // B1: xt + lmask(prev z) visible

        // prev-step z masks -> SGPRs (wave-uniform)
        unsigned mk[NB][4];
        #pragma unroll
        for (int nb = 0; nb < NB; ++nb) {
            #pragma unroll
            for (int q = 0; q < 4; ++q)
                mk[nb][q] = (unsigned)__builtin_amdgcn_readfirstlane((int)lmask[nb][q]);
        }

        // dropout mask (coalesced: lanes = consecutive h)
        float mreg[NB];
        #pragma unroll
        for (int nb = 0; nb < NB; ++nb)
            mreg[nb] = dm[((size_t)t * BTOT + (size_t)(bbase + nb)) * HDIM + hh];

        // input-current contribution: x_t @ w_in.T
        float inp[NB];
        #pragma unroll
        for (int nb = 0; nb < NB; ++nb) {
            float s0 = 0.f;
            #pragma unroll
            for (int s = 0; s < 8; ++s) s0 += xt[nb][s] * win[s];
            inp[nb] = s0;
        }

        // recurrent contribution: z_prev @ w_rec.T  (z bits from SGPR masks, w in VGPRs)
        float acc0[NB], acc1[NB];
        #pragma unroll
        for (int nb = 0; nb < NB; ++nb) { acc0[nb] = 0.f; acc1[nb] = 0.f; }
        #pragma unroll
        for (int j = 0; j < HDIM; ++j) {
            const float wj = w[j];
            #pragma unroll
            for (int nb = 0; nb < NB; ++nb) {
                float zj = __uint_as_float(((mk[nb][j >> 5] >> (j & 31)) & 1u) * 0x3f800000u);
                if (j & 1) acc1[nb] = fmaf(zj, wj, acc1[nb]);
                else       acc0[nb] = fmaf(zj, wj, acc0[nb]);
            }
        }

        // elementwise LSNN cell
        float zn[NB];
        #pragma unroll
        for (int nb = 0; nb < NB; ++nb) {
            float v_dec = v[nb] + 0.1f * (cur[nb] - v[nb]);
            float i_dec = cur[nb] - 0.2f * cur[nb];
            float b_dec = ba[nb] + KA * (1.0f - ba[nb]);
            float z = (v_dec - b_dec > 0.f) ? 1.f : 0.f;
            v[nb]  = (1.f - z) * v_dec;
            ba[nb] = b_dec + z * KB;
            cur[nb] = i_dec + inp[nb] + (acc0[nb] + acc1[nb]);
            zn[nb] = z;
        }

        // readout partial sums: (z_new * m_t) @ w_out.T, per-wave butterfly reduce
        #pragma unroll
        for (int nb = 0; nb < NB; ++nb) {
            float zd = zn[nb] * mreg[nb];
            float r0 = zd * wout0, r1 = zd * wout1;
            #pragma unroll
            for (int off = 32; off > 0; off >>= 1) {
                r0 += __shfl_xor(r0, off);
                r1 += __shfl_xor(r1, off);
            }
            if (lane == 0) { red[nb][wv][0] = r0; red[nb][wv][1] = r1; }
        }
        __syncthreads();   // B2: red visible; all mask reads done

        // publish new z masks for next step
        #pragma unroll
        for (int nb = 0; nb < NB; ++nb) {
            unsigned long long bm = __ballot(zn[nb] > 0.5f);
            if (lane == 0) {
                lmask[nb][wv * 2 + 0] = (unsigned)(bm & 0xffffffffULL);
                lmask[nb][wv * 2 + 1] = (unsigned)(bm >> 32);
            }
        }

        // LI readout update (thread 0; state in LDS, trivial cost)
        if (hh == 0) {
            #pragma unroll
            for (int nb = 0; nb < NB; ++nb) {
                float r0 = red[nb][0][0] + red[nb][1][0];
                float r1 = red[nb][0][1] + red[nb][1][1];
                float vo0 = rout[nb][0], vo1 = rout[nb][1];
                float io0 = rout[nb][2], io1 = rout[nb][3];
                vo0 = vo0 + 0.1f * (io0 - vo0);
                vo1 = vo1 + 0.1f * (io1 - vo1);
                io0 = io0 - 0.2f * io0 + r0;
                io1 = io1 - 0.2f * io1 + r1;
                rout[nb][0] = vo0; rout[nb][1] = vo1;
                rout[nb][2] = io0; rout[nb][3] = io1;
                rout[nb][4] = fmaxf(rout[nb][4], vo0);
                rout[nb][5] = fmaxf(rout[nb][5], vo1);
            }
        }
    }
    __syncthreads();

    if (hh == 0) {
        #pragma unroll
        for (int nb = 0; nb < NB; ++nb) {
            float m0 = rout[nb][4], m1 = rout[nb][5];
            float mx = fmaxf(m0, m1);
            float e0 = expf(m0 - mx), e1 = expf(m1 - mx);
            float s = e0 + e1;
            out[(bbase + nb) * 2 + 0] = e0 / s;
            out[(bbase + nb) * 2 + 1] = e1 / s;
        }
    }
}

extern "C" void kernel_launch(void* const* d_in, const int* in_sizes, int n_in,
                              void* d_out, int out_size, void* d_ws, size_t ws_size,
                              hipStream_t stream) {
    const float* x     = (const float*)d_in[0];
    const float* w_in  = (const float*)d_in[1];
    const float* w_rec = (const float*)d_in[2];
    const float* w_out = (const float*)d_in[3];
    const float* dmask = (const float*)d_in[4];
    float* outp = (float*)d_out;

    lsnn_kernel<<<BTOT / NB, BLK, 0, stream>>>(x, w_in, w_rec, w_out, dmask, outp);
}

// Round 3
// 564.835 us; speedup vs baseline: 4.0347x; 4.0347x over previous
//
#include <hip/hip_runtime.h>
#include <math.h>
#include <string.h>

#define TSTEPS 40
#define BTOT   16384
#define HDIM   128
#define BT     16            // batch rows per block
#define NWAVE  8             // waves per block (one 16-col h-slice each)

typedef __attribute__((ext_vector_type(8))) short bf16x8;
typedef __attribute__((ext_vector_type(4))) float f32x4;

// round-to-nearest-even fp32 -> bf16 (bit trick; inputs finite)
__device__ __forceinline__ short f2bf(float f) {
    unsigned int u;
    memcpy(&u, &f, 4);
    unsigned int lsb = (u >> 16) & 1u;
    u += 0x7fffu + lsb;
    return (short)(u >> 16);
}
__device__ __forceinline__ float bf2f(short s) {
    unsigned int u = ((unsigned int)(unsigned short)s) << 16;
    float f;
    memcpy(&f, &u, 4);
    return f;
}

__global__ __launch_bounds__(512, 2)
void lsnn_mfma(const float* __restrict__ x,
               const float* __restrict__ w_in,
               const float* __restrict__ w_rec,
               const float* __restrict__ w_out,
               const float* __restrict__ dm,
               float* __restrict__ out)
{
    __shared__ short zbuf[BT][136];    // z_{t-1} bf16, padded stride (bank spread)
    __shared__ short xt[BT][8];        // encoder spikes bf16
    __shared__ float red[NWAVE][BT][2];// readout partials

    const int tid   = threadIdx.x;
    const int l     = tid & 63;
    const int wv    = tid >> 6;
    const int li    = l & 15;          // tile col / A row
    const int q     = l >> 4;          // k-group / C row-group
    const int bbase = blockIdx.x * BT;
    const int hcol  = wv * 16 + li;    // this lane's hidden column

    // ---- B-operand weight fragments, 3-way bf16 split, registers-resident ----
    // B[k][j] = w_rec[h = wv*16+j][k]; lane l holds k = kt*32 + q*8 + i, j = li
    bf16x8 wB[4][3];
    #pragma unroll
    for (int kt = 0; kt < 4; ++kt) {
        const float* src = w_rec + hcol * HDIM + kt * 32 + q * 8;
        #pragma unroll
        for (int i = 0; i < 8; ++i) {
            float w0 = src[i];
            short h0 = f2bf(w0); float r1 = w0 - bf2f(h0);
            short h1 = f2bf(r1); float r2 = r1 - bf2f(h1);
            short h2 = f2bf(r2);
            wB[kt][0][i] = h0; wB[kt][1][i] = h1; wB[kt][2][i] = h2;
        }
    }
    // w_in fragments: B[k][j] = w_in[h][k], only k<8 nonzero (K padded 8->32)
    bf16x8 wiB[3];
    #pragma unroll
    for (int p = 0; p < 3; ++p)
        #pragma unroll
        for (int i = 0; i < 8; ++i) wiB[p][i] = 0;
    if (q == 0) {
        const float* src = w_in + hcol * 8;
        #pragma unroll
        for (int i = 0; i < 8; ++i) {
            float w0 = src[i];
            short h0 = f2bf(w0); float r1 = w0 - bf2f(h0);
            short h1 = f2bf(r1); float r2 = r1 - bf2f(h1);
            short h2 = f2bf(r2);
            wiB[0][i] = h0; wiB[1][i] = h1; wiB[2][i] = h2;
        }
    }
    const float wo0 = w_out[hcol];
    const float wo1 = w_out[HDIM + hcol];

    // ---- state ----
    f32x4 v  = {0.f, 0.f, 0.f, 0.f};
    f32x4 cu = {0.f, 0.f, 0.f, 0.f};
    f32x4 ba = {0.f, 0.f, 0.f, 0.f};

    // encoder: waves 0-1, 128 lanes cover (row 0..15) x (ch 0..7)
    float ve = 0.f, ce = 0.f;
    const int g = wv * 64 + l;
    if (wv < 2) {
        int er = g >> 3, ech = g & 7;
        float xv = 50.f * x[(bbase + er) * 4 + (ech & 3)];
        ce = (ech < 4) ? fmaxf(xv, 0.f) : fmaxf(-xv, 0.f);
    }
    // readout state: wave 0 lanes 0..31 hold (row = l>>1, o = l&1)
    float vo = 0.f, io = 0.f, mx = 0.f;

    const float KA = 1.4285714285714286e-06f;  // DT * (1/700)
    const float KB = 2.5714285714285714e-03f;  // (1/700) * 1.8

    // zero z_{-1}
    for (int idx = tid; idx < BT * 136; idx += 512) ((short*)zbuf)[idx] = 0;
    __syncthreads();

    // dm prefetch for t=0
    float mr[4];
    {
        const float* dmt = dm + (size_t)bbase * HDIM;
        #pragma unroll
        for (int r = 0; r < 4; ++r) mr[r] = dmt[(q * 4 + r) * HDIM + hcol];
    }

    for (int t = 0; t < TSTEPS; ++t) {
        // ---- phase a: encoder step + read z_prev A-fragments ----
        float sp = 0.f;
        if (wv < 2) {
            float vv = ve + 0.1f * (ce - ve);
            sp = (vv - 1.0f > 0.f) ? 1.f : 0.f;
            ve = (1.f - sp) * vv;
        }
        bf16x8 zA[4];
        #pragma unroll
        for (int kt = 0; kt < 4; ++kt)
            zA[kt] = *reinterpret_cast<const bf16x8*>(&zbuf[li][kt * 32 + q * 8]);
        if (wv < 2) xt[g >> 3][g & 7] = (sp > 0.5f) ? (short)0x3F80 : (short)0;
        __syncthreads();   // B1: xt visible; zbuf reads complete

        // ---- phase c: prefetch next dm, then MFMA accumulation ----
        float mrn[4];
        {
            int tn = (t + 1 < TSTEPS) ? t + 1 : TSTEPS - 1;
            const float* dmn = dm + ((size_t)tn * BTOT + bbase) * HDIM;
            #pragma unroll
            for (int r = 0; r < 4; ++r) mrn[r] = dmn[(q * 4 + r) * HDIM + hcol];
        }
        bf16x8 xA;
        #pragma unroll
        for (int i = 0; i < 8; ++i) xA[i] = 0;
        if (q == 0) xA = *reinterpret_cast<const bf16x8*>(&xt[li][0]);

        f32x4 acc = {0.f, 0.f, 0.f, 0.f};
        #pragma unroll
        for (int p = 0; p < 3; ++p) {
            acc = __builtin_amdgcn_mfma_f32_16x16x32_bf16(xA, wiB[p], acc, 0, 0, 0);
            #pragma unroll
            for (int kt = 0; kt < 4; ++kt)
                acc = __builtin_amdgcn_mfma_f32_16x16x32_bf16(zA[kt], wB[kt][p], acc, 0, 0, 0);
        }

        // ---- phase d: elementwise LSNN cell on C-layout fragments ----
        float p0r[4], p1r[4];
        #pragma unroll
        for (int r = 0; r < 4; ++r) {
            float vd = v[r] + 0.1f * (cu[r] - v[r]);
            float id = cu[r] - 0.2f * cu[r];
            float bd = ba[r] + KA * (1.0f - ba[r]);
            float z  = (vd - bd > 0.f) ? 1.f : 0.f;
            v[r]  = (1.f - z) * vd;
            ba[r] = bd + z * KB;
            cu[r] = id + acc[r];
            float zd = z * mr[r];
            p0r[r] = zd * wo0;
            p1r[r] = zd * wo1;
            zbuf[q * 4 + r][hcol] = (z > 0.5f) ? (short)0x3F80 : (short)0;
        }
        // reduce readout partials across the 16 cols of this wave's h-slice
        #pragma unroll
        for (int s = 1; s < 16; s <<= 1) {
            #pragma unroll
            for (int r = 0; r < 4; ++r) {
                p0r[r] += __shfl_xor(p0r[r], s);
                p1r[r] += __shfl_xor(p1r[r], s);
            }
        }
        if (li == 0) {
            #pragma unroll
            for (int r = 0; r < 4; ++r) {
                red[wv][q * 4 + r][0] = p0r[r];
                red[wv][q * 4 + r][1] = p1r[r];
            }
        }
        __syncthreads();   // B2: zbuf + red visible

        // ---- phase f: LI readout (wave 0, lanes 0..31) ----
        if (wv == 0 && l < 32) {
            int row = l >> 1, o = l & 1;
            float s = 0.f;
            #pragma unroll
            for (int w = 0; w < NWAVE; ++w) s += red[w][row][o];
            float von = vo + 0.1f * (io - vo);
            io = io - 0.2f * io + s;
            vo = von;
            mx = fmaxf(mx, vo);
        }
        #pragma unroll
        for (int r = 0; r < 4; ++r) mr[r] = mrn[r];
    }

    // ---- epilogue: softmax over the 2 logits, write out ----
    if (wv == 0 && l < 32) {
        int row = l >> 1, o = l & 1;
        float other = __shfl_xor(mx, 1);
        float mmax  = fmaxf(mx, other);
        float e  = expf(mx - mmax);
        float eo = expf(other - mmax);
        out[(size_t)(bbase + row) * 2 + o] = e / (e + eo);
    }
}

extern "C" void kernel_launch(void* const* d_in, const int* in_sizes, int n_in,
                              void* d_out, int out_size, void* d_ws, size_t ws_size,
                              hipStream_t stream) {
    const float* x     = (const float*)d_in[0];
    const float* w_in  = (const float*)d_in[1];
    const float* w_rec = (const float*)d_in[2];
    const float* w_out = (const float*)d_in[3];
    const float* dmask = (const float*)d_in[4];
    float* outp = (float*)d_out;

    lsnn_mfma<<<BTOT / BT, 512, 0, stream>>>(x, w_in, w_rec, w_out, dmask, outp);
}

// Round 4
// 533.560 us; speedup vs baseline: 4.2712x; 1.0586x over previous
//
#include <hip/hip_runtime.h>
#include <math.h>
#include <string.h>

#define TSTEPS 40
#define BTOT   16384
#define HDIM   128
#define BT     64            // batch rows per block -> 256 blocks = 1/CU
#define NWAVE  8
#define ZSTR   136           // zbuf row stride in shorts (16B-aligned, bank-spread)

typedef __attribute__((ext_vector_type(8))) short bf16x8;
typedef __attribute__((ext_vector_type(4))) float f32x4;

__device__ __forceinline__ short f2bf(float f) {
    unsigned int u;
    memcpy(&u, &f, 4);
    unsigned int lsb = (u >> 16) & 1u;
    u += 0x7fffu + lsb;
    return (short)(u >> 16);
}
__device__ __forceinline__ float bf2f(short s) {
    unsigned int u = ((unsigned int)(unsigned short)s) << 16;
    float f;
    memcpy(&f, &u, 4);
    return f;
}

__global__ __launch_bounds__(512, 2)
void lsnn_mfma64(const float* __restrict__ x,
                 const float* __restrict__ w_in,
                 const float* __restrict__ w_rec,
                 const float* __restrict__ w_out,
                 const float* __restrict__ dm,
                 float* __restrict__ out)
{
    __shared__ short zbuf[BT][ZSTR];     // z_{t-1} bf16
    __shared__ short xt[BT][8];          // encoder spikes bf16
    __shared__ float red[NWAVE][BT][2];  // readout partials

    const int tid   = threadIdx.x;
    const int l     = tid & 63;
    const int wv    = tid >> 6;
    const int li    = l & 15;            // B col / A row within tile
    const int q     = l >> 4;            // k-group / C row-group
    const int bbase = blockIdx.x * BT;
    const int hcol  = wv * 16 + li;

    // ---- register-resident weights, 3-way bf16 split ----
    bf16x8 wB[4][3];
    #pragma unroll
    for (int kt = 0; kt < 4; ++kt) {
        const float* src = w_rec + hcol * HDIM + kt * 32 + q * 8;
        #pragma unroll
        for (int i = 0; i < 8; ++i) {
            float w0 = src[i];
            short h0 = f2bf(w0); float r1 = w0 - bf2f(h0);
            short h1 = f2bf(r1); float r2 = r1 - bf2f(h1);
            short h2 = f2bf(r2);
            wB[kt][0][i] = h0; wB[kt][1][i] = h1; wB[kt][2][i] = h2;
        }
    }
    bf16x8 wiB[3];
    #pragma unroll
    for (int p = 0; p < 3; ++p)
        #pragma unroll
        for (int i = 0; i < 8; ++i) wiB[p][i] = 0;
    if (q == 0) {
        const float* src = w_in + hcol * 8;
        #pragma unroll
        for (int i = 0; i < 8; ++i) {
            float w0 = src[i];
            short h0 = f2bf(w0); float r1 = w0 - bf2f(h0);
            short h1 = f2bf(r1); float r2 = r1 - bf2f(h1);
            short h2 = f2bf(r2);
            wiB[0][i] = h0; wiB[1][i] = h1; wiB[2][i] = h2;
        }
    }
    const float wo0 = w_out[hcol];
    const float wo1 = w_out[HDIM + hcol];

    // ---- per-row-tile LSNN state (C-fragment layout: row = rt*16 + q*4 + r) ----
    f32x4 v[4], cu[4], ba[4];
    #pragma unroll
    for (int rt = 0; rt < 4; ++rt) {
        v[rt]  = (f32x4){0.f, 0.f, 0.f, 0.f};
        cu[rt] = (f32x4){0.f, 0.f, 0.f, 0.f};
        ba[rt] = (f32x4){0.f, 0.f, 0.f, 0.f};
    }

    // ---- encoder: 512 threads = 64 rows x 8 channels ----
    const int er = tid >> 3, ech = tid & 7;
    float ve = 0.f, ce;
    {
        float xv = 50.f * x[(bbase + er) * 4 + (ech & 3)];
        ce = (ech < 4) ? fmaxf(xv, 0.f) : fmaxf(-xv, 0.f);
    }

    // ---- readout state: waves 0-1, slot g = wv*64+l -> (row = g>>1, o = g&1) ----
    float vo = 0.f, io = 0.f, mx = 0.f;

    const float KA = 1.4285714285714286e-06f;  // DT * (1/700)
    const float KB = 2.5714285714285714e-03f;  // (1/700) * 1.8

    for (int idx = tid; idx < BT * ZSTR; idx += 512) ((short*)zbuf)[idx] = 0;
    __syncthreads();

    // dm prefetch for t=0
    float mr[4][4];
    {
        const float* dmt = dm + (size_t)bbase * HDIM;
        #pragma unroll
        for (int rt = 0; rt < 4; ++rt)
            #pragma unroll
            for (int r = 0; r < 4; ++r)
                mr[rt][r] = dmt[(rt * 16 + q * 4 + r) * HDIM + hcol];
    }

    for (int t = 0; t < TSTEPS; ++t) {
        // ---- encoder step (writes x_t used this step) ----
        {
            float vv = ve + 0.1f * (ce - ve);
            float sp = (vv - 1.0f > 0.f) ? 1.f : 0.f;
            ve = (1.f - sp) * vv;
            xt[er][ech] = (sp > 0.5f) ? (short)0x3F80 : (short)0;
        }

        // ---- recurrent MFMAs (depend only on z_{t-1}; run before B1) ----
        f32x4 acc[4];
        #pragma unroll
        for (int rt = 0; rt < 4; ++rt) {
            bf16x8 zA[4];
            #pragma unroll
            for (int kt = 0; kt < 4; ++kt)
                zA[kt] = *reinterpret_cast<const bf16x8*>(&zbuf[rt * 16 + li][kt * 32 + q * 8]);
            f32x4 a = {0.f, 0.f, 0.f, 0.f};
            #pragma unroll
            for (int p = 0; p < 3; ++p)
                #pragma unroll
                for (int kt = 0; kt < 4; ++kt)
                    a = __builtin_amdgcn_mfma_f32_16x16x32_bf16(zA[kt], wB[kt][p], a, 0, 0, 0);
            acc[rt] = a;
        }
        __syncthreads();   // B1: xt visible; all zbuf reads complete

        // ---- prefetch dm for t+1 (hides HBM latency under rest of step) ----
        float mrn[4][4];
        {
            int tn = (t + 1 < TSTEPS) ? t + 1 : TSTEPS - 1;
            const float* dmn = dm + ((size_t)tn * BTOT + bbase) * HDIM;
            #pragma unroll
            for (int rt = 0; rt < 4; ++rt)
                #pragma unroll
                for (int r = 0; r < 4; ++r)
                    mrn[rt][r] = dmn[(rt * 16 + q * 4 + r) * HDIM + hcol];
        }

        // ---- input-current MFMAs ----
        #pragma unroll
        for (int rt = 0; rt < 4; ++rt) {
            bf16x8 xA;
            #pragma unroll
            for (int i = 0; i < 8; ++i) xA[i] = 0;
            if (q == 0) xA = *reinterpret_cast<const bf16x8*>(&xt[rt * 16 + li][0]);
            #pragma unroll
            for (int p = 0; p < 3; ++p)
                acc[rt] = __builtin_amdgcn_mfma_f32_16x16x32_bf16(xA, wiB[p], acc[rt], 0, 0, 0);
        }

        // ---- elementwise cell + z publish + readout partial reduce ----
        #pragma unroll
        for (int rt = 0; rt < 4; ++rt) {
            float p0r[4], p1r[4];
            #pragma unroll
            for (int r = 0; r < 4; ++r) {
                float vd = v[rt][r] + 0.1f * (cu[rt][r] - v[rt][r]);
                float id = cu[rt][r] - 0.2f * cu[rt][r];
                float bd = ba[rt][r] + KA * (1.0f - ba[rt][r]);
                float z  = (vd - bd > 0.f) ? 1.f : 0.f;
                v[rt][r]  = (1.f - z) * vd;
                ba[rt][r] = bd + z * KB;
                cu[rt][r] = id + acc[rt][r];
                zbuf[rt * 16 + q * 4 + r][hcol] = (z > 0.5f) ? (short)0x3F80 : (short)0;
                float zd = z * mr[rt][r];
                p0r[r] = zd * wo0;
                p1r[r] = zd * wo1;
            }
            #pragma unroll
            for (int s = 1; s < 16; s <<= 1) {
                #pragma unroll
                for (int r = 0; r < 4; ++r) {
                    p0r[r] += __shfl_xor(p0r[r], s);
                    p1r[r] += __shfl_xor(p1r[r], s);
                }
            }
            if (li == 0) {
                #pragma unroll
                for (int r = 0; r < 4; ++r) {
                    red[wv][rt * 16 + q * 4 + r][0] = p0r[r];
                    red[wv][rt * 16 + q * 4 + r][1] = p1r[r];
                }
            }
        }
        __syncthreads();   // B2: zbuf + red visible

        // ---- LI readout: waves 0-1 own (row, o) slots ----
        if (wv < 2) {
            int g = wv * 64 + l;
            int row = g >> 1, o = g & 1;
            float s = 0.f;
            #pragma unroll
            for (int w = 0; w < NWAVE; ++w) s += red[w][row][o];
            float von = vo + 0.1f * (io - vo);
            io = io - 0.2f * io + s;
            vo = von;
            mx = fmaxf(mx, vo);
        }
        #pragma unroll
        for (int rt = 0; rt < 4; ++rt)
            #pragma unroll
            for (int r = 0; r < 4; ++r) mr[rt][r] = mrn[rt][r];
    }

    // ---- epilogue: softmax over 2 logits ----
    if (wv < 2) {
        int g = wv * 64 + l;
        int row = g >> 1;
        int o = g & 1;
        float other = __shfl_xor(mx, 1);
        float mmax  = fmaxf(mx, other);
        float e  = expf(mx - mmax);
        float eo = expf(other - mmax);
        out[(size_t)(bbase + row) * 2 + o] = e / (e + eo);
    }
}

extern "C" void kernel_launch(void* const* d_in, const int* in_sizes, int n_in,
                              void* d_out, int out_size, void* d_ws, size_t ws_size,
                              hipStream_t stream) {
    const float* x     = (const float*)d_in[0];
    const float* w_in  = (const float*)d_in[1];
    const float* w_rec = (const float*)d_in[2];
    const float* w_out = (const float*)d_in[3];
    const float* dmask = (const float*)d_in[4];
    float* outp = (float*)d_out;

    lsnn_mfma64<<<BTOT / BT, 512, 0, stream>>>(x, w_in, w_rec, w_out, dmask, outp);
}